// Round 12
// baseline (364.529 us; speedup 1.0000x reference)
//
#include <hip/hip_runtime.h>
#include <hip/hip_bf16.h>

typedef unsigned short u16t;
typedef __attribute__((ext_vector_type(8))) short bf16x8;
typedef __attribute__((ext_vector_type(4))) short bf16x4;
typedef __attribute__((ext_vector_type(4))) float f32x4;

#define Bn 32
#define Nn 64
#define Fd 64
#define DMd 128
#define DMOd 64
#define OMd 128
#define En 4096

#define NTEN 36
#define TOTALC 1073217
#define HP 136              // padded LDS row stride (u16) for 128-wide h (16B-aligned rows)
#define UP 264              // padded LDS row stride (u16) for 256-wide u
#define XP 72               // padded LDS row stride (u16) for 64-wide x tile
#define WSEG 131072         // per-layer u16 count of repacked weights

__device__ const int kOffs[NTEN + 1] = {
    0,        131072,   393216,   458752,   459264,   475648,   492032,   557568,
    558080,   574464,   590848,   656384,   656896,   673280,   689664,   722432,
    722688,   853760,   854272,   919808,   920320,   985856,   986368,   1019136,
    1019392,  1027584,  1027712,  1044096,  1044224,  1060608,  1060736,  1068928,
    1068992,  1073088,  1073152,  1073216,  1073217
};

#define C_NF    0
#define C_VEC   131072
#define C_MW1   393216
#define C_MB1   458752
#define C_G1    459264
#define C_BB1   475648
#define C_MW2   492032
#define C_MB2   557568
#define C_G2    558080
#define C_BB2   574464
#define C_MW3   590848
#define C_MB3   656384
#define C_G3    656896
#define C_BB3   673280
#define C_MW4   689664
#define C_MB4   722432
#define C_UW1   722688
#define C_UB1   853760
#define C_UW2   854272
#define C_UB2   919808
#define C_UW3   920320
#define C_UB3   985856
#define C_UW4   986368
#define C_UB4   1019136
#define C_PW1   1019392
#define C_PB1   1027584
#define C_PW2   1027712
#define C_PB2   1044096
#define C_PW3   1044224
#define C_PB3   1060608
#define C_PW4   1060736
#define C_PB4   1068928
#define C_QW1   1068992
#define C_QB1   1073088
#define C_QW2   1073152
#define C_QB2   1073216

// per-layer segment bases (u16) inside repacked weight region
#define S_W2T 0
#define S_W3T 16384
#define S_W4T 32768
#define S_U1T 40960
#define S_U2T 73728
#define S_U3T 90112
#define S_U4T 106496
#define S_W1T 114688

// ---- dead-conversion trim: only these C ranges are read after repack+colsums ----
__device__ const int liveStart[9] = {0, C_MB1, C_MB2, C_MB3, C_MB4, C_UB1, C_UB2, C_UB3, C_UB4};
__device__ const int livePre[10]  = {0, 393216, 426496, 459776, 493056, 493312, 493824, 494336, 494848, 548929};
#define NCOMPACT 548929

// block-range partition of the fused prep kernel
#define NB_CONV 2145
#define NB_PREPW 2048
#define NB_CS 5
#define NB_PQ0 1024
#define NB_PREP (NB_CONV + NB_PREPW + NB_CS + NB_PQ0)

struct Ptrs { const void* p[NTEN]; };

__device__ __forceinline__ float us2f(u16t u) {
    return __uint_as_float(((unsigned int)u) << 16);
}
__device__ __forceinline__ u16t f2us(float f) {
    __hip_bfloat16 h = __float2bfloat16(f);
    return *reinterpret_cast<u16t*>(&h);
}
// fast swish: v_exp + v_rcp (~1e-7 rel err) instead of full-precision fp32 divide
__device__ __forceinline__ float swishf(float x) {
    return x * __builtin_amdgcn_rcpf(1.0f + __expf(-x));
}
// load element idx from a raw tensor that is either bf16 or fp32
__device__ __forceinline__ float ldcvt(const void* p, int idx, int flag) {
    return flag ? us2f(((const u16t*)p)[idx]) : ((const float*)p)[idx];
}
__device__ __forceinline__ int get_flag(const void* g1raw) {
    return (((const u16t*)g1raw)[0] == 0x3F80u) ? 1 : 0;
}

// ---------- fused prep: convert(live-only) + weight repack + colsums + layer-0 P,Q ----------
__global__ __launch_bounds__(256) void k_prep(Ptrs t, float* __restrict__ C,
                                              float* __restrict__ x,
                                              u16t* __restrict__ W,
                                              float* __restrict__ CS,
                                              float* __restrict__ P,
                                              float* __restrict__ Q,
                                              float* __restrict__ agg) {
    const int flag = get_flag(t.p[4]);   // bn1_g
    const int blk = blockIdx.x;
    const int tid = threadIdx.x;

    if (blk < NB_CONV) {
        // ---- convert LIVE inputs to canonical fp32; NF feeds x only (C_NF unread) ----
        int i = blk * 256 + tid;
        if (i >= NCOMPACT) return;
        int lo = 0, hi = 9;
        while (hi - lo > 1) { int m = (lo + hi) >> 1; if (i >= livePre[m]) lo = m; else hi = m; }
        const int Cidx = liveStart[lo] + (i - livePre[lo]);
        int lo2 = 0, hi2 = NTEN;
        while (hi2 - lo2 > 1) { int m = (lo2 + hi2) >> 1; if (Cidx >= kOffs[m]) lo2 = m; else hi2 = m; }
        float v = ldcvt(t.p[lo2], Cidx - kOffs[lo2], flag);
        if (Cidx < Bn * Nn * Fd) x[Cidx] = v;
        else                     C[Cidx] = v;
    } else if (blk < NB_CONV + NB_PREPW) {
        // ---- repack GEMM weights into bf16 [n][k], reading raw directly ----
        int i = (blk - NB_CONV) * 256 + tid;
        const int l = i / WSEG;
        int r = i - l * WSEG;
        int tens, local;
        if (r < S_W3T)      { int q = r;          int n = q >> 7, k = q & 127; tens = 6;  local = l*16384 + k*128 + n; }
        else if (r < S_W4T) { int q = r - S_W3T;  int n = q >> 7, k = q & 127; tens = 10; local = l*16384 + k*128 + n; }
        else if (r < S_U1T) { int q = r - S_W4T;  int n = q >> 7, k = q & 127; tens = 14; local = l*8192  + k*64  + n; }
        else if (r < S_U2T) { int q = r - S_U1T;  int n = q >> 8, k = q & 255; tens = 16; local = l*32768 + k*128 + n; }
        else if (r < S_U3T) { int q = r - S_U2T;  int n = q >> 7, k = q & 127; tens = 18; local = l*16384 + k*128 + n; }
        else if (r < S_U4T) { int q = r - S_U3T;  int n = q >> 7, k = q & 127; tens = 20; local = l*16384 + k*128 + n; }
        else if (r < S_W1T) { int q = r - S_U4T;  int n = q >> 7, k = q & 127; tens = 22; local = l*8192  + k*64  + n; }
        else                { int q = r - S_W1T;  int n = q >> 7, k = q & 127; tens = 2;  local = l*16384 + k*128 + n; }
        W[i] = f2us(ldcvt(t.p[tens], local, flag));
    } else if (blk < NB_CONV + NB_PREPW + NB_CS) {
        // ---- per-layer colsums of bf16-rounded W2/W3/W4 (BN-fold term) ----
        int i = (blk - NB_CONV - NB_PREPW) * 256 + tid;
        if (i >= 4 * 320) return;
        const int l = i / 320, j = i - l * 320;
        const void* tp; int base, stride;
        if (j < 128)      { tp = t.p[6];  base = l*16384 + j;         stride = 128; }
        else if (j < 256) { tp = t.p[10]; base = l*16384 + (j - 128); stride = 128; }
        else              { tp = t.p[14]; base = l*8192  + (j - 256); stride = 64; }
        float s = 0.f;
        #pragma unroll 8
        for (int k = 0; k < 128; k++) s += us2f(f2us(ldcvt(tp, base + k * stride, flag)));
        CS[i] = s;
    } else {
        // ---- layer-0 P,Q (2 nodes/block) + zero agg; P gets msg_b1[0] folded in ----
        const int rel = blk - (NB_CONV + NB_PREPW + NB_CS);
        const int gid = rel * 256 + tid;
        if (gid < Bn * Nn * DMOd) agg[gid] = 0.f;
        __shared__ float xr2[2][Fd];
        const int half = tid >> 7, t7 = tid & 127;
        const int bn = rel * 2 + half;
        if (t7 < Fd) xr2[half][t7] = ldcvt(t.p[0], bn * Fd + t7, flag);
        __syncthreads();
        float accP = 0.f, accQ = 0.f;
        if (flag) {
            const u16t* W1 = (const u16t*)t.p[2];
            #pragma unroll 8
            for (int k = 0; k < Fd; k++) {
                float xv = xr2[half][k];
                accP += xv * us2f(W1[k * DMd + t7]);
                accQ += xv * us2f(W1[(Fd + k) * DMd + t7]);
            }
        } else {
            const float* W1 = (const float*)t.p[2];
            #pragma unroll 8
            for (int k = 0; k < Fd; k++) {
                float xv = xr2[half][k];
                accP += xv * W1[k * DMd + t7];
                accQ += xv * W1[(Fd + k) * DMd + t7];
            }
        }
        P[bn * DMd + t7] = accP + ldcvt(t.p[3], t7, flag);   // fold msg_b1[layer 0]
        Q[bn * DMd + t7] = accQ;
    }
}

// ---------- wave reduction of 8 partials, lane0 posts to rd[wv] ----------
__device__ __forceinline__ void wave_red8(float* s, float (*rd)[8], int wv, int lane) {
    #pragma unroll
    for (int off = 32; off > 0; off >>= 1)
        #pragma unroll
        for (int k = 0; k < 8; k++) s[k] += __shfl_down(s[k], off);
    if (lane == 0) {
        #pragma unroll
        for (int k = 0; k < 8; k++) rd[wv][k] = s[k];
    }
}

// ---------- per-thread (redundant) BN affine from posted partials ----------
// y = a*u + c  with  a = rstd*g[e],  c = bb[e] - mean*a
__device__ __forceinline__ void calc_ab(const float (*rd)[8],
                                        const float* __restrict__ g,
                                        const float* __restrict__ bb,
                                        int src0, int dst,
                                        float* a, float* c) {
    #pragma unroll
    for (int e = 0; e < 4; e++) {
        float S  = rd[0][2*e]   + rd[1][2*e]   + rd[2][2*e]   + rd[3][2*e];
        float S2 = rd[0][2*e+1] + rd[1][2*e+1] + rd[2][2*e+1] + rd[3][2*e+1];
        float mean = S * (1.0f / 4096.0f);
        float var  = S2 * (1.0f / 4096.0f) - mean * mean;
        float av = rsqrtf(var + 1e-5f) * g[(src0 + e) * Nn + dst];
        a[e] = av;
        c[e] = bb[(src0 + e) * Nn + dst] - mean * av;
    }
}

// ---- one t-half of stages 2/3: acc[4][2] (32 regs) -> epilogue -> PK (static idx) ----
#define STAGE_HALF(TH, PK)                                                            \
    {                                                                                 \
        f32x4 acc[4][2];                                                              \
        _Pragma("unroll")                                                             \
        for (int e = 0; e < 4; e++) {                                                 \
            acc[e][0] = (f32x4){0.f, 0.f, 0.f, 0.f};                                  \
            acc[e][1] = (f32x4){0.f, 0.f, 0.f, 0.f};                                  \
        }                                                                             \
        _Pragma("unroll")                                                             \
        for (int ks = 0; ks < 4; ks++) {                                              \
            bf16x8 wb[2];                                                             \
            _Pragma("unroll")                                                         \
            for (int t2 = 0; t2 < 2; t2++)                                            \
                wb[t2] = *(const bf16x8*)&Wt[(nBase + ((TH)*2 + t2) * 16 + l15) * 128 \
                                             + ks * 32 + quad * 8];                   \
            _Pragma("unroll")                                                         \
            for (int e = 0; e < 4; e++) {                                             \
                bf16x8 a8 = *(const bf16x8*)&hE[e][mrow * HP + ks * 32 + quad * 8];   \
                acc[e][0] = __builtin_amdgcn_mfma_f32_16x16x32_bf16(wb[0], a8, acc[e][0], 0, 0, 0); \
                acc[e][1] = __builtin_amdgcn_mfma_f32_16x16x32_bf16(wb[1], a8, acc[e][1], 0, 0, 0); \
            }                                                                         \
        }                                                                             \
        _Pragma("unroll")                                                             \
        for (int e = 0; e < 4; e++) {                                                 \
            const float ae = aP[e], ce = cP[e];                                       \
            _Pragma("unroll")                                                         \
            for (int t2 = 0; t2 < 2; t2++) {                                          \
                const int n0 = nBase + ((TH)*2 + t2) * 16 + quad * 4;                 \
                float4 c4  = *(const float4*)&cv[n0];                                 \
                float4 bb4 = *(const float4*)&bv[n0];                                 \
                _Pragma("unroll")                                                     \
                for (int r = 0; r < 4; r++) {                                         \
                    float z = ae * acc[e][t2][r] + (ce * (&c4.x)[r] + (&bb4.x)[r]);   \
                    float u = swishf(z);                                              \
                    s[2*e] += u; s[2*e+1] += u * u;                                   \
                    PK[e][t2][r] = (short)f2us(u);                                    \
                }                                                                     \
            }                                                                         \
        }                                                                             \
    }

// ---------- fused per-edge message MLP: 4 edges (same dst) per block ----------
// (256,4): 1024 = 4 x 256 slots, no tail. Register plan vs r11: stages 2/3 run
// as TWO NAMED t-halves (acc[4][2]=32 regs each; pkA/pkB separately named so
// every index is compile-time-constant — runtime-indexed arrays go to scratch).
// sched_barrier(0) between halves stops the scheduler re-fusing them.
// Failure signature: WRITE_SIZE > 20 MB (spill beyond source control).
__global__ __launch_bounds__(256, 4) void k_edge(
    const float* __restrict__ P, const float* __restrict__ Q,
    const float* __restrict__ g1, const float* __restrict__ bb1,
    const u16t* __restrict__ W2t, const float* __restrict__ b2v, const float* __restrict__ cs2,
    const float* __restrict__ g2, const float* __restrict__ bb2,
    const u16t* __restrict__ W3t, const float* __restrict__ b3v, const float* __restrict__ cs3,
    const float* __restrict__ g3, const float* __restrict__ bb3,
    const u16t* __restrict__ W4t, const float* __restrict__ b4v, const float* __restrict__ cs4,
    float* __restrict__ agg) {
    __shared__ u16t hE[4][Bn * HP];      // 4 edges × 8704 B, holds raw u (pre-BN)
    __shared__ float red[2][4][8];       // ping-pong sum/sumsq partials per wave

    const int dst = blockIdx.x & 63, src0 = (blockIdx.x >> 6) * 4;
    const int tid = threadIdx.x;
    const int wv = tid >> 6, lane = tid & 63, quad = lane >> 4, l15 = lane & 15;
    const int mw = wv & 1, nb2 = wv >> 1;
    const int mrow = mw * 16 + l15;
    const int nBase = nb2 * 64;

    // ---- lin1: u1 = swish(P[b,dst]+Q[b,src]); store raw u1; post sums ----
    // (msg_b1 is pre-folded into P)
    {
        const int b = tid >> 3, d0 = (tid & 7) * 16;
        float4 pv[4];
        {
            const float4* pp = (const float4*)&P[(b * Nn + dst) * DMd + d0];
            #pragma unroll
            for (int j = 0; j < 4; j++) pv[j] = pp[j];
        }
        float s[8];
        #pragma unroll
        for (int e = 0; e < 4; e++) {
            const float4* qq = (const float4*)&Q[(b * Nn + src0 + e) * DMd + d0];
            float u[16];
            #pragma unroll
            for (int j = 0; j < 4; j++) {
                float4 qv = qq[j];
                u[j*4+0] = swishf(pv[j].x + qv.x);
                u[j*4+1] = swishf(pv[j].y + qv.y);
                u[j*4+2] = swishf(pv[j].z + qv.z);
                u[j*4+3] = swishf(pv[j].w + qv.w);
            }
            float se = 0.f, s2e = 0.f;
            #pragma unroll
            for (int i = 0; i < 16; i++) { se += u[i]; s2e += u[i] * u[i]; }
            bf16x8 s0, s1;
            #pragma unroll
            for (int j = 0; j < 8; j++) {
                s0[j] = (short)f2us(u[j]);
                s1[j] = (short)f2us(u[8 + j]);
            }
            *(bf16x8*)&hE[e][b * HP + d0]     = s0;
            *(bf16x8*)&hE[e][b * HP + d0 + 8] = s1;
            s[2*e] = se; s[2*e+1] = s2e;
        }
        wave_red8(s, red[0], wv, lane);
    }
    __syncthreads();

    float aP[4], cP[4];
    calc_ab(red[0], g1, bb1, src0, dst, aP, cP);

    // ---- stages 2 & 3: acc = u_{k-1} @ W ; u = swish(a*acc + c*colsum + bias) ----
    // Swapped MFMA (mfma(W,h)): lane holds 4 consecutive cols of one row.
    #pragma unroll 1
    for (int st = 0; st < 2; st++) {
        const u16t*  Wt = st ? W3t : W2t;
        const float* bv = st ? b3v : b2v;
        const float* cv = st ? cs3 : cs2;
        bf16x4 pkA[4][2], pkB[4][2];
        float s[8];
        #pragma unroll
        for (int k = 0; k < 8; k++) s[k] = 0.f;
        STAGE_HALF(0, pkA)
        __builtin_amdgcn_sched_barrier(0);   // keep halves sequential (liveness cap)
        STAGE_HALF(1, pkB)
        wave_red8(s, red[1 - st], wv, lane);
        __syncthreads();   // all MFMA reads of hE done; red[1-st] fully posted
        calc_ab(red[1 - st], st ? g3 : g2, st ? bb3 : bb2, src0, dst, aP, cP);
        // write-back: swapped C-layout -> lane owns row mrow, 4 consecutive cols
        #pragma unroll
        for (int e = 0; e < 4; e++) {
            *(bf16x4*)&hE[e][mrow * HP + nBase +  0 + quad * 4] = pkA[e][0];
            *(bf16x4*)&hE[e][mrow * HP + nBase + 16 + quad * 4] = pkA[e][1];
            *(bf16x4*)&hE[e][mrow * HP + nBase + 32 + quad * 4] = pkB[e][0];
            *(bf16x4*)&hE[e][mrow * HP + nBase + 48 + quad * 4] = pkB[e][1];
        }
        __syncthreads();   // u_k visible for next stage
    }

    // ---- stage 4: m = swish(a3*(u3@W4) + c3*colsum(W4) + b4); sum 4 edges; atomics ----
    // UNSWAPPED orientation: keeps the 64B-coalesced atomicAdd address pattern.
    {
        const int n40 = nb2 * 32;
        f32x4 a4[4][2];
        #pragma unroll
        for (int e = 0; e < 4; e++) {
            a4[e][0] = (f32x4){0.f, 0.f, 0.f, 0.f};
            a4[e][1] = (f32x4){0.f, 0.f, 0.f, 0.f};
        }
        #pragma unroll
        for (int ks = 0; ks < 4; ks++) {
            bf16x8 wb[2];
            #pragma unroll
            for (int t = 0; t < 2; t++)
                wb[t] = *(const bf16x8*)&W4t[(n40 + t * 16 + l15) * 128 + ks * 32 + quad * 8];
            #pragma unroll
            for (int e = 0; e < 4; e++) {
                bf16x8 a8 = *(const bf16x8*)&hE[e][mrow * HP + ks * 32 + quad * 8];
                #pragma unroll
                for (int t = 0; t < 2; t++)
                    a4[e][t] = __builtin_amdgcn_mfma_f32_16x16x32_bf16(a8, wb[t], a4[e][t], 0, 0, 0);
            }
        }
        #pragma unroll
        for (int t = 0; t < 2; t++) {
            const int col = n40 + t * 16 + l15;
            const float csv = cs4[col], bvv = b4v[col];
            float fe[4];
            #pragma unroll
            for (int e = 0; e < 4; e++) fe[e] = cP[e] * csv + bvv;
            #pragma unroll
            for (int r = 0; r < 4; r++) {
                float m = swishf(aP[0] * a4[0][t][r] + fe[0])
                        + swishf(aP[1] * a4[1][t][r] + fe[1])
                        + swishf(aP[2] * a4[2][t][r] + fe[2])
                        + swishf(aP[3] * a4[3][t][r] + fe[3]);
                const int b = mw * 16 + quad * 4 + r;
                atomicAdd(&agg[(b * Nn + dst) * DMOd + col], m);
            }
        }
    }
}

// ---------- node update MLP + fused next-layer P,Q + agg zeroing ----------
// 16 nodes/block, 128 blocks
__global__ __launch_bounds__(256, 4) void k_updq(
    const float* __restrict__ vC, float* __restrict__ x, float* __restrict__ agg,
    const u16t* __restrict__ U1t, const float* __restrict__ b1,
    const u16t* __restrict__ U2t, const float* __restrict__ b2,
    const u16t* __restrict__ U3t, const float* __restrict__ b3,
    const u16t* __restrict__ U4t, const float* __restrict__ b4,
    const u16t* __restrict__ W1Tn, const float* __restrict__ b1n,
    float* __restrict__ Pn, float* __restrict__ Qn,
    int doPQ) {
    __shared__ u16t uL[16 * UP];   // 8448 B
    __shared__ u16t hL[16 * HP];   // 4352 B
    __shared__ u16t xL[16 * XP];   // 2304 B
    const int g0 = blockIdx.x * 16;
    const int tid = threadIdx.x;
    const int wv = tid >> 6, lane = tid & 63, quad = lane >> 4, l15 = lane & 15;
    const int nBase = wv * 32;

    // stage u = [vec | x | agg/64] as bf16
    {
        const int i = tid >> 4, c0 = (tid & 15) * 16;
        const int g = g0 + i;
        const float* srcp; float scl = 1.f;
        if (c0 < 128)       srcp = &vC[g * OMd + c0];
        else if (c0 < 192)  srcp = &x[g * Fd + (c0 - 128)];
        else              { srcp = &agg[g * DMOd + (c0 - 192)]; scl = 1.0f / 64.0f; }
        bf16x8 s0, s1;
        #pragma unroll
        for (int j = 0; j < 8; j++) {
            s0[j] = (short)f2us(srcp[j] * scl);
            s1[j] = (short)f2us(srcp[8 + j] * scl);
        }
        *(bf16x8*)&uL[i * UP + c0]     = s0;
        *(bf16x8*)&uL[i * UP + c0 + 8] = s1;
    }
    __syncthreads();

    // gemm1: (16x256)@(256x128) -> hL
    {
        f32x4 acc[2];
        #pragma unroll
        for (int t = 0; t < 2; t++) {
            float b0 = b1[nBase + t * 16 + l15];
            acc[t] = (f32x4){b0, b0, b0, b0};
        }
        #pragma unroll
        for (int ks = 0; ks < 8; ks++) {
            bf16x8 a8 = *(const bf16x8*)&uL[l15 * UP + ks * 32 + quad * 8];
            #pragma unroll
            for (int t = 0; t < 2; t++) {
                bf16x8 b8 = *(const bf16x8*)&U1t[(nBase + t * 16 + l15) * 256 + ks * 32 + quad * 8];
                acc[t] = __builtin_amdgcn_mfma_f32_16x16x32_bf16(a8, b8, acc[t], 0, 0, 0);
            }
        }
        #pragma unroll
        for (int t = 0; t < 2; t++)
            #pragma unroll
            for (int r = 0; r < 4; r++)
                hL[(quad * 4 + r) * HP + nBase + t * 16 + l15] = f2us(swishf(acc[t][r]));
    }
    __syncthreads();

    // gemm2, gemm3: (16x128)@(128x128) in-place on hL
    #pragma unroll 1
    for (int st = 0; st < 2; st++) {
        const u16t*  Ut = st ? U3t : U2t;
        const float* bb = st ? b3  : b2;
        f32x4 acc[2];
        #pragma unroll
        for (int t = 0; t < 2; t++) {
            float b0 = bb[nBase + t * 16 + l15];
            acc[t] = (f32x4){b0, b0, b0, b0};
        }
        #pragma unroll
        for (int ks = 0; ks < 4; ks++) {
            bf16x8 a8 = *(const bf16x8*)&hL[l15 * HP + ks * 32 + quad * 8];
            #pragma unroll
            for (int t = 0; t < 2; t++) {
                bf16x8 b8 = *(const bf16x8*)&Ut[(nBase + t * 16 + l15) * 128 + ks * 32 + quad * 8];
                acc[t] = __builtin_amdgcn_mfma_f32_16x16x32_bf16(a8, b8, acc[t], 0, 0, 0);
            }
        }
        __syncthreads();   // all reads of hL done
        #pragma unroll
        for (int t = 0; t < 2; t++)
            #pragma unroll
            for (int r = 0; r < 4; r++)
                hL[(quad * 4 + r) * HP + nBase + t * 16 + l15] = f2us(swishf(acc[t][r]));
        __syncthreads();
    }

    // gemm4: (16x128)@(128x64); residual into x (global fp32 + LDS bf16)
    {
        const int n4 = wv * 16;
        f32x4 acc;
        {
            float b0 = b4[n4 + l15];
            acc = (f32x4){b0, b0, b0, b0};
        }
        #pragma unroll
        for (int ks = 0; ks < 4; ks++) {
            bf16x8 a8 = *(const bf16x8*)&hL[l15 * HP + ks * 32 + quad * 8];
            bf16x8 b8 = *(const bf16x8*)&U4t[(n4 + l15) * 128 + ks * 32 + quad * 8];
            acc = __builtin_amdgcn_mfma_f32_16x16x32_bf16(a8, b8, acc, 0, 0, 0);
        }
        #pragma unroll
        for (int r = 0; r < 4; r++) {
            int row = quad * 4 + r, col = n4 + l15;
            float xn = x[(g0 + row) * Fd + col] + swishf(acc[r]);
            x[(g0 + row) * Fd + col] = xn;
            xL[row * XP + col] = f2us(xn);
        }
    }

    // zero this block's agg rows for the next layer
    {
        int idx = tid;
        #pragma unroll
        for (int k = 0; k < 4; k++, idx += 256) agg[g0 * DMOd + idx] = 0.f;
    }
    __syncthreads();

    // fused next-layer P,Q: (16x64) @ W1T -> P,Q rows; P gets b1 of next layer
    if (doPQ) {
        f32x4 ap[2], aq[2];
        #pragma unroll
        for (int j = 0; j < 2; j++) { ap[j] = (f32x4){0,0,0,0}; aq[j] = (f32x4){0,0,0,0}; }
        #pragma unroll
        for (int ks = 0; ks < 2; ks++) {
            bf16x8 a8 = *(const bf16x8*)&xL[l15 * XP + ks * 32 + quad * 8];
            #pragma unroll
            for (int j = 0; j < 2; j++) {
                const int n0 = (wv * 2 + j) * 16 + l15;
                bf16x8 bp = *(const bf16x8*)&W1Tn[n0 * 128 + ks * 32 + quad * 8];
                bf16x8 bq = *(const bf16x8*)&W1Tn[n0 * 128 + 64 + ks * 32 + quad * 8];
                ap[j] = __builtin_amdgcn_mfma_f32_16x16x32_bf16(a8, bp, ap[j], 0, 0, 0);
                aq[j] = __builtin_amdgcn_mfma_f32_16x16x32_bf16(a8, bq, aq[j], 0, 0, 0);
            }
        }
        #pragma unroll
        for (int j = 0; j < 2; j++)
            #pragma unroll
            for (int r = 0; r < 4; r++) {
                int g = g0 + quad * 4 + r, col = (wv * 2 + j) * 16 + l15;
                Pn[g * DMd + col] = ap[j][r] + b1n[col];
                Qn[g * DMd + col] = aq[j][r];
            }
    }
}

// ---------- pre/post heads -> c, plus v passthrough ----------
__global__ __launch_bounds__(128) void k_final(
    const float* __restrict__ x, const void* __restrict__ vraw,
    const float* __restrict__ pW1, const float* __restrict__ pb1,
    const float* __restrict__ pW2, const float* __restrict__ pb2,
    const float* __restrict__ pW3, const float* __restrict__ pb3,
    const float* __restrict__ pW4, const float* __restrict__ pb4,
    const float* __restrict__ qW1, const float* __restrict__ qb1,
    const float* __restrict__ qW2, const float* __restrict__ qb2,
    float* __restrict__ c_buf, void* __restrict__ out, const void* __restrict__ g1raw) {
    __shared__ float xr[64];
    __shared__ float ha[128];
    __shared__ float hb[128];
    __shared__ float hc[64];
    __shared__ float tt[64];
    const int bn = blockIdx.x;
    const int tid = threadIdx.x;
    const int flag = get_flag(g1raw);
    if (tid < 64) xr[tid] = x[bn * Fd + tid];
    __syncthreads();
    float acc = pb1[tid];
    #pragma unroll 8
    for (int k = 0; k < 64; k++) acc += xr[k] * pW1[k * 128 + tid];
    ha[tid] = swishf(acc);
    __syncthreads();
    acc = pb2[tid];
    #pragma unroll 8
    for (int k = 0; k < 128; k++) acc += ha[k] * pW2[k * 128 + tid];
    hb[tid] = swishf(acc);
    __syncthreads();
    acc = pb3[tid];
    #pragma unroll 8
    for (int k = 0; k < 128; k++) acc += hb[k] * pW3[k * 128 + tid];
    ha[tid] = swishf(acc);
    __syncthreads();
    if (tid < 64) {
        acc = pb4[tid];
        #pragma unroll 8
        for (int k = 0; k < 128; k++) acc += ha[k] * pW4[k * 64 + tid];
        hc[tid] = acc;
    }
    __syncthreads();
    if (tid < 64) {
        acc = qb1[tid];
        #pragma unroll 8
        for (int k = 0; k < 64; k++) acc += hc[k] * qW1[k * 64 + tid];
        tt[tid] = swishf(acc);
    }
    __syncthreads();
    if (tid < 64) {
        float p = tt[tid] * qW2[tid];
        #pragma unroll
        for (int off = 32; off > 0; off >>= 1) p += __shfl_down(p, off);
        if (tid == 0) {
            float cv = p + qb2[0];
            c_buf[bn] = cv;
            const int ci = 4096 + Bn * Nn * OMd + bn;
            if (flag) ((u16t*)out)[ci] = f2us(cv);
            else      ((float*)out)[ci] = cv;
        }
    }
    const int vi = bn * OMd + tid;
    if (flag) ((u16t*)out)[4096 + vi] = ((const u16t*)vraw)[vi];
    else      ((float*)out)[4096 + vi] = ((const float*)vraw)[vi];
}

// ---------- x3[b,d] = sum_n v[b,n,d] * c[b,n] ----------
__global__ __launch_bounds__(128) void k_x3(const float* __restrict__ vC,
                                            const float* __restrict__ c_buf,
                                            void* __restrict__ out,
                                            const void* __restrict__ g1raw) {
    const int b = blockIdx.x, d = threadIdx.x;
    const int flag = get_flag(g1raw);
    float acc = 0.f;
    #pragma unroll 4
    for (int n = 0; n < Nn; n++)
        acc += vC[(b * Nn + n) * OMd + d] * c_buf[b * Nn + n];
    if (flag) ((u16t*)out)[b * OMd + d] = f2us(acc);
    else      ((float*)out)[b * OMd + d] = acc;
}

extern "C" void kernel_launch(void* const* d_in, const int* in_sizes, int n_in,
                              void* d_out, int out_size, void* d_ws, size_t ws_size,
                              hipStream_t stream) {
    float* ws = (float*)d_ws;
    float* C     = ws + 16;
    float* x     = C + 1073664;
    float* P     = x + 131072;
    float* Q     = P + 262144;
    float* agg   = Q + 262144;
    float* c_buf = agg + 131072;
    u16t*  Wt    = (u16t*)(c_buf + 2048);   // 4*WSEG u16 = 1 MB
    float* CS    = (float*)(Wt + 4 * WSEG); // 4*320 fp32 colsums

    Ptrs t;
    for (int i = 0, j = 0; i < 37; i++) {
        if (i == 2) continue;
        t.p[j++] = d_in[i];
    }

    k_prep<<<NB_PREP, 256, 0, stream>>>(t, C, x, Wt, CS, P, Q, agg);

    for (int l = 0; l < 4; l++) {
        u16t* Wl = Wt + l * WSEG;
        float* CSl = CS + l * 320;
        k_edge<<<64 * 16, 256, 0, stream>>>(
            P, Q,
            C + C_G1 + l * En, C + C_BB1 + l * En,
            Wl + S_W2T, C + C_MB2 + l * DMd, CSl,
            C + C_G2 + l * En, C + C_BB2 + l * En,
            Wl + S_W3T, C + C_MB3 + l * DMd, CSl + 128,
            C + C_G3 + l * En, C + C_BB3 + l * En,
            Wl + S_W4T, C + C_MB4 + l * DMOd, CSl + 256,
            agg);
        const int doPQ = (l < 3) ? 1 : 0;
        const u16t* W1Tn = Wt + (doPQ ? (l + 1) : 0) * WSEG + S_W1T;
        const float* b1n = C + C_MB1 + (doPQ ? (l + 1) : 0) * DMd;
        k_updq<<<Bn * Nn / 16, 256, 0, stream>>>(
            C + C_VEC, x, agg,
            Wl + S_U1T, C + C_UB1 + l * DMd,
            Wl + S_U2T, C + C_UB2 + l * DMd,
            Wl + S_U3T, C + C_UB3 + l * DMd,
            Wl + S_U4T, C + C_UB4 + l * DMOd,
            W1Tn, b1n, P, Q, doPQ);
    }

    k_final<<<Bn * Nn, 128, 0, stream>>>(x, d_in[1],
        C + C_PW1, C + C_PB1, C + C_PW2, C + C_PB2,
        C + C_PW3, C + C_PB3, C + C_PW4, C + C_PB4,
        C + C_QW1, C + C_QB1, C + C_QW2, C + C_QB2,
        c_buf, d_out, d_in[5]);
    k_x3<<<Bn, 128, 0, stream>>>(C + C_VEC, c_buf, d_out, d_in[5]);
}

// Round 13
// 360.858 us; speedup vs baseline: 1.0102x; 1.0102x over previous
//
#include <hip/hip_runtime.h>
#include <hip/hip_bf16.h>

typedef unsigned short u16t;
typedef __attribute__((ext_vector_type(8))) short bf16x8;
typedef __attribute__((ext_vector_type(4))) short bf16x4;
typedef __attribute__((ext_vector_type(4))) float f32x4;

#define Bn 32
#define Nn 64
#define Fd 64
#define DMd 128
#define DMOd 64
#define OMd 128
#define En 4096

#define NTEN 36
#define TOTALC 1073217
#define HP 136              // padded LDS row stride (u16) for 128-wide h (16B-aligned rows)
#define UP 264              // padded LDS row stride (u16) for 256-wide u
#define XP 72               // padded LDS row stride (u16) for 64-wide x tile
#define WSEG 131072         // per-layer u16 count of repacked weights

__device__ const int kOffs[NTEN + 1] = {
    0,        131072,   393216,   458752,   459264,   475648,   492032,   557568,
    558080,   574464,   590848,   656384,   656896,   673280,   689664,   722432,
    722688,   853760,   854272,   919808,   920320,   985856,   986368,   1019136,
    1019392,  1027584,  1027712,  1044096,  1044224,  1060608,  1060736,  1068928,
    1068992,  1073088,  1073152,  1073216,  1073217
};

#define C_NF    0
#define C_VEC   131072
#define C_MW1   393216
#define C_MB1   458752
#define C_G1    459264
#define C_BB1   475648
#define C_MW2   492032
#define C_MB2   557568
#define C_G2    558080
#define C_BB2   574464
#define C_MW3   590848
#define C_MB3   656384
#define C_G3    656896
#define C_BB3   673280
#define C_MW4   689664
#define C_MB4   722432
#define C_UW1   722688
#define C_UB1   853760
#define C_UW2   854272
#define C_UB2   919808
#define C_UW3   920320
#define C_UB3   985856
#define C_UW4   986368
#define C_UB4   1019136
#define C_PW1   1019392
#define C_PB1   1027584
#define C_PW2   1027712
#define C_PB2   1044096
#define C_PW3   1044224
#define C_PB3   1060608
#define C_PW4   1060736
#define C_PB4   1068928
#define C_QW1   1068992
#define C_QB1   1073088
#define C_QW2   1073152
#define C_QB2   1073216

// per-layer segment bases (u16) inside repacked weight region
#define S_W2T 0
#define S_W3T 16384
#define S_W4T 32768
#define S_U1T 40960
#define S_U2T 73728
#define S_U3T 90112
#define S_U4T 106496
#define S_W1T 114688

// ---- dead-conversion trim: only these C ranges are read after repack+colsums ----
__device__ const int liveStart[9] = {0, C_MB1, C_MB2, C_MB3, C_MB4, C_UB1, C_UB2, C_UB3, C_UB4};
__device__ const int livePre[10]  = {0, 393216, 426496, 459776, 493056, 493312, 493824, 494336, 494848, 548929};
#define NCOMPACT 548929

// block-range partition of the fused prep kernel
#define NB_CONV 2145
#define NB_PREPW 2048
#define NB_CS 5
#define NB_PQ0 1024
#define NB_PREP (NB_CONV + NB_PREPW + NB_CS + NB_PQ0)

struct Ptrs { const void* p[NTEN]; };

__device__ __forceinline__ float us2f(u16t u) {
    return __uint_as_float(((unsigned int)u) << 16);
}
__device__ __forceinline__ u16t f2us(float f) {
    __hip_bfloat16 h = __float2bfloat16(f);
    return *reinterpret_cast<u16t*>(&h);
}
// fast swish: v_exp + v_rcp (~1e-7 rel err) instead of full-precision fp32 divide
__device__ __forceinline__ float swishf(float x) {
    return x * __builtin_amdgcn_rcpf(1.0f + __expf(-x));
}
// load element idx from a raw tensor that is either bf16 or fp32
__device__ __forceinline__ float ldcvt(const void* p, int idx, int flag) {
    return flag ? us2f(((const u16t*)p)[idx]) : ((const float*)p)[idx];
}
__device__ __forceinline__ int get_flag(const void* g1raw) {
    return (((const u16t*)g1raw)[0] == 0x3F80u) ? 1 : 0;
}

// ---------- fused prep: convert(live-only) + weight repack + colsums + layer-0 P,Q ----------
__global__ __launch_bounds__(256) void k_prep(Ptrs t, float* __restrict__ C,
                                              float* __restrict__ x,
                                              u16t* __restrict__ W,
                                              float* __restrict__ CS,
                                              float* __restrict__ P,
                                              float* __restrict__ Q,
                                              float* __restrict__ agg) {
    const int flag = get_flag(t.p[4]);   // bn1_g
    const int blk = blockIdx.x;
    const int tid = threadIdx.x;

    if (blk < NB_CONV) {
        // ---- convert LIVE inputs to canonical fp32; NF feeds x only (C_NF unread) ----
        int i = blk * 256 + tid;
        if (i >= NCOMPACT) return;
        int lo = 0, hi = 9;
        while (hi - lo > 1) { int m = (lo + hi) >> 1; if (i >= livePre[m]) lo = m; else hi = m; }
        const int Cidx = liveStart[lo] + (i - livePre[lo]);
        int lo2 = 0, hi2 = NTEN;
        while (hi2 - lo2 > 1) { int m = (lo2 + hi2) >> 1; if (Cidx >= kOffs[m]) lo2 = m; else hi2 = m; }
        float v = ldcvt(t.p[lo2], Cidx - kOffs[lo2], flag);
        if (Cidx < Bn * Nn * Fd) x[Cidx] = v;
        else                     C[Cidx] = v;
    } else if (blk < NB_CONV + NB_PREPW) {
        // ---- repack GEMM weights into bf16 [n][k], reading raw directly ----
        int i = (blk - NB_CONV) * 256 + tid;
        const int l = i / WSEG;
        int r = i - l * WSEG;
        int tens, local;
        if (r < S_W3T)      { int q = r;          int n = q >> 7, k = q & 127; tens = 6;  local = l*16384 + k*128 + n; }
        else if (r < S_W4T) { int q = r - S_W3T;  int n = q >> 7, k = q & 127; tens = 10; local = l*16384 + k*128 + n; }
        else if (r < S_U1T) { int q = r - S_W4T;  int n = q >> 7, k = q & 127; tens = 14; local = l*8192  + k*64  + n; }
        else if (r < S_U2T) { int q = r - S_U1T;  int n = q >> 8, k = q & 255; tens = 16; local = l*32768 + k*128 + n; }
        else if (r < S_U3T) { int q = r - S_U2T;  int n = q >> 7, k = q & 127; tens = 18; local = l*16384 + k*128 + n; }
        else if (r < S_U4T) { int q = r - S_U3T;  int n = q >> 7, k = q & 127; tens = 20; local = l*16384 + k*128 + n; }
        else if (r < S_W1T) { int q = r - S_U4T;  int n = q >> 7, k = q & 127; tens = 22; local = l*8192  + k*64  + n; }
        else                { int q = r - S_W1T;  int n = q >> 7, k = q & 127; tens = 2;  local = l*16384 + k*128 + n; }
        W[i] = f2us(ldcvt(t.p[tens], local, flag));
    } else if (blk < NB_CONV + NB_PREPW + NB_CS) {
        // ---- per-layer colsums of bf16-rounded W2/W3/W4 (BN-fold term) ----
        int i = (blk - NB_CONV - NB_PREPW) * 256 + tid;
        if (i >= 4 * 320) return;
        const int l = i / 320, j = i - l * 320;
        const void* tp; int base, stride;
        if (j < 128)      { tp = t.p[6];  base = l*16384 + j;         stride = 128; }
        else if (j < 256) { tp = t.p[10]; base = l*16384 + (j - 128); stride = 128; }
        else              { tp = t.p[14]; base = l*8192  + (j - 256); stride = 64; }
        float s = 0.f;
        #pragma unroll 8
        for (int k = 0; k < 128; k++) s += us2f(f2us(ldcvt(tp, base + k * stride, flag)));
        CS[i] = s;
    } else {
        // ---- layer-0 P,Q (2 nodes/block) + zero agg; P gets msg_b1[0] folded in ----
        const int rel = blk - (NB_CONV + NB_PREPW + NB_CS);
        const int gid = rel * 256 + tid;
        if (gid < Bn * Nn * DMOd) agg[gid] = 0.f;
        __shared__ float xr2[2][Fd];
        const int half = tid >> 7, t7 = tid & 127;
        const int bn = rel * 2 + half;
        if (t7 < Fd) xr2[half][t7] = ldcvt(t.p[0], bn * Fd + t7, flag);
        __syncthreads();
        float accP = 0.f, accQ = 0.f;
        if (flag) {
            const u16t* W1 = (const u16t*)t.p[2];
            #pragma unroll 8
            for (int k = 0; k < Fd; k++) {
                float xv = xr2[half][k];
                accP += xv * us2f(W1[k * DMd + t7]);
                accQ += xv * us2f(W1[(Fd + k) * DMd + t7]);
            }
        } else {
            const float* W1 = (const float*)t.p[2];
            #pragma unroll 8
            for (int k = 0; k < Fd; k++) {
                float xv = xr2[half][k];
                accP += xv * W1[k * DMd + t7];
                accQ += xv * W1[(Fd + k) * DMd + t7];
            }
        }
        P[bn * DMd + t7] = accP + ldcvt(t.p[3], t7, flag);   // fold msg_b1[layer 0]
        Q[bn * DMd + t7] = accQ;
    }
}

// ---------- wave reduction of 8 partials, lane0 posts to rd[wv] ----------
__device__ __forceinline__ void wave_red8(float* s, float (*rd)[8], int wv, int lane) {
    #pragma unroll
    for (int off = 32; off > 0; off >>= 1)
        #pragma unroll
        for (int k = 0; k < 8; k++) s[k] += __shfl_down(s[k], off);
    if (lane == 0) {
        #pragma unroll
        for (int k = 0; k < 8; k++) rd[wv][k] = s[k];
    }
}

// ---------- per-thread (redundant) BN affine from posted partials ----------
// y = a*u + c  with  a = rstd*g[e],  c = bb[e] - mean*a
__device__ __forceinline__ void calc_ab(const float (*rd)[8],
                                        const float* __restrict__ g,
                                        const float* __restrict__ bb,
                                        int src0, int dst,
                                        float* a, float* c) {
    #pragma unroll
    for (int e = 0; e < 4; e++) {
        float S  = rd[0][2*e]   + rd[1][2*e]   + rd[2][2*e]   + rd[3][2*e];
        float S2 = rd[0][2*e+1] + rd[1][2*e+1] + rd[2][2*e+1] + rd[3][2*e+1];
        float mean = S * (1.0f / 4096.0f);
        float var  = S2 * (1.0f / 4096.0f) - mean * mean;
        float av = rsqrtf(var + 1e-5f) * g[(src0 + e) * Nn + dst];
        a[e] = av;
        c[e] = bb[(src0 + e) * Nn + dst] - mean * av;
    }
}

// ---------- fused per-edge message MLP: 4 edges (same dst) per block ----------
// BEST MEASURED CONFIG (round-11 bench, 46.3 us): (256,4), pk-before-barrier
// epilogue, NO order pinning. The ~24-32 MB spill traffic is accepted: it hides
// under compute (~1 TB/s << HBM roofline) and every spill-avoidance variant
// (r9 hoist-diet, r12 split+sched_barrier) measured SLOWER — scheduling freedom
// beats register thrift on this kernel.
__global__ __launch_bounds__(256, 4) void k_edge(
    const float* __restrict__ P, const float* __restrict__ Q,
    const float* __restrict__ g1, const float* __restrict__ bb1,
    const u16t* __restrict__ W2t, const float* __restrict__ b2v, const float* __restrict__ cs2,
    const float* __restrict__ g2, const float* __restrict__ bb2,
    const u16t* __restrict__ W3t, const float* __restrict__ b3v, const float* __restrict__ cs3,
    const float* __restrict__ g3, const float* __restrict__ bb3,
    const u16t* __restrict__ W4t, const float* __restrict__ b4v, const float* __restrict__ cs4,
    float* __restrict__ agg) {
    __shared__ u16t hE[4][Bn * HP];      // 4 edges × 8704 B, holds raw u (pre-BN)
    __shared__ float red[2][4][8];       // ping-pong sum/sumsq partials per wave

    const int dst = blockIdx.x & 63, src0 = (blockIdx.x >> 6) * 4;
    const int tid = threadIdx.x;
    const int wv = tid >> 6, lane = tid & 63, quad = lane >> 4, l15 = lane & 15;
    const int mw = wv & 1, nb2 = wv >> 1;
    const int mrow = mw * 16 + l15;
    const int nBase = nb2 * 64;

    // ---- lin1: u1 = swish(P[b,dst]+Q[b,src]); store raw u1; post sums ----
    // (msg_b1 is pre-folded into P)
    {
        const int b = tid >> 3, d0 = (tid & 7) * 16;
        float4 pv[4];
        {
            const float4* pp = (const float4*)&P[(b * Nn + dst) * DMd + d0];
            #pragma unroll
            for (int j = 0; j < 4; j++) pv[j] = pp[j];
        }
        float s[8];
        #pragma unroll
        for (int e = 0; e < 4; e++) {
            const float4* qq = (const float4*)&Q[(b * Nn + src0 + e) * DMd + d0];
            float u[16];
            #pragma unroll
            for (int j = 0; j < 4; j++) {
                float4 qv = qq[j];
                u[j*4+0] = swishf(pv[j].x + qv.x);
                u[j*4+1] = swishf(pv[j].y + qv.y);
                u[j*4+2] = swishf(pv[j].z + qv.z);
                u[j*4+3] = swishf(pv[j].w + qv.w);
            }
            float se = 0.f, s2e = 0.f;
            #pragma unroll
            for (int i = 0; i < 16; i++) { se += u[i]; s2e += u[i] * u[i]; }
            bf16x8 s0, s1;
            #pragma unroll
            for (int j = 0; j < 8; j++) {
                s0[j] = (short)f2us(u[j]);
                s1[j] = (short)f2us(u[8 + j]);
            }
            *(bf16x8*)&hE[e][b * HP + d0]     = s0;
            *(bf16x8*)&hE[e][b * HP + d0 + 8] = s1;
            s[2*e] = se; s[2*e+1] = s2e;
        }
        wave_red8(s, red[0], wv, lane);
    }
    __syncthreads();

    float aP[4], cP[4];
    calc_ab(red[0], g1, bb1, src0, dst, aP, cP);

    // ---- stages 2 & 3: acc = u_{k-1} @ W ; u = swish(a*acc + c*colsum + bias) ----
    // MFMA operands swapped (mfma(W,h)): lane holds 4 consecutive cols of one row.
    #pragma unroll 1
    for (int st = 0; st < 2; st++) {
        const u16t*  Wt = st ? W3t : W2t;
        const float* bv = st ? b3v : b2v;
        const float* cv = st ? cs3 : cs2;
        f32x4 acc[4][4];
        #pragma unroll
        for (int e = 0; e < 4; e++)
            #pragma unroll
            for (int t = 0; t < 4; t++) acc[e][t] = (f32x4){0.f, 0.f, 0.f, 0.f};
        #pragma unroll
        for (int ks = 0; ks < 4; ks++) {
            bf16x8 wb[4];
            #pragma unroll
            for (int t = 0; t < 4; t++)
                wb[t] = *(const bf16x8*)&Wt[(nBase + t * 16 + l15) * 128 + ks * 32 + quad * 8];
            #pragma unroll
            for (int e = 0; e < 4; e++) {
                bf16x8 a8 = *(const bf16x8*)&hE[e][mrow * HP + ks * 32 + quad * 8];
                #pragma unroll
                for (int t = 0; t < 4; t++)
                    acc[e][t] = __builtin_amdgcn_mfma_f32_16x16x32_bf16(wb[t], a8, acc[e][t], 0, 0, 0);
            }
        }
        // epilogue: convert acc -> packed bf16 pk BEFORE the barrier.
        // Only pk (32 regs) + posted sums survive the barrier; acc dies here.
        bf16x4 pk[4][4];
        float s[8];
        #pragma unroll
        for (int e = 0; e < 4; e++) {
            const float ae = aP[e], ce = cP[e];
            float se = 0.f, s2e = 0.f;
            #pragma unroll
            for (int t = 0; t < 4; t++) {
                const int n0 = nBase + t * 16 + quad * 4;
                float4 c4  = *(const float4*)&cv[n0];
                float4 bb4 = *(const float4*)&bv[n0];
                #pragma unroll
                for (int r = 0; r < 4; r++) {
                    float z = ae * acc[e][t][r] + (ce * (&c4.x)[r] + (&bb4.x)[r]);
                    float u = swishf(z);
                    se += u; s2e += u * u;
                    pk[e][t][r] = (short)f2us(u);
                }
            }
            s[2*e] = se; s[2*e+1] = s2e;
        }
        wave_red8(s, red[1 - st], wv, lane);
        __syncthreads();   // all MFMA reads of hE done; red[1-st] fully posted
        calc_ab(red[1 - st], st ? g3 : g2, st ? bb3 : bb2, src0, dst, aP, cP);
        // write-back: swapped C-layout -> lane owns row mrow, 4 consecutive cols
        #pragma unroll
        for (int e = 0; e < 4; e++)
            #pragma unroll
            for (int t = 0; t < 4; t++)
                *(bf16x4*)&hE[e][mrow * HP + nBase + t * 16 + quad * 4] = pk[e][t];
        __syncthreads();   // u_k visible for next stage
    }

    // ---- stage 4: m = swish(a3*(u3@W4) + c3*colsum(W4) + b4); sum 4 edges; atomics ----
    // UNSWAPPED orientation: keeps the 64B-coalesced atomicAdd address pattern.
    {
        const int n40 = nb2 * 32;
        f32x4 a4[4][2];
        #pragma unroll
        for (int e = 0; e < 4; e++) {
            a4[e][0] = (f32x4){0.f, 0.f, 0.f, 0.f};
            a4[e][1] = (f32x4){0.f, 0.f, 0.f, 0.f};
        }
        #pragma unroll
        for (int ks = 0; ks < 4; ks++) {
            bf16x8 wb[2];
            #pragma unroll
            for (int t = 0; t < 2; t++)
                wb[t] = *(const bf16x8*)&W4t[(n40 + t * 16 + l15) * 128 + ks * 32 + quad * 8];
            #pragma unroll
            for (int e = 0; e < 4; e++) {
                bf16x8 a8 = *(const bf16x8*)&hE[e][mrow * HP + ks * 32 + quad * 8];
                #pragma unroll
                for (int t = 0; t < 2; t++)
                    a4[e][t] = __builtin_amdgcn_mfma_f32_16x16x32_bf16(a8, wb[t], a4[e][t], 0, 0, 0);
            }
        }
        #pragma unroll
        for (int t = 0; t < 2; t++) {
            const int col = n40 + t * 16 + l15;
            const float csv = cs4[col], bvv = b4v[col];
            float fe[4];
            #pragma unroll
            for (int e = 0; e < 4; e++) fe[e] = cP[e] * csv + bvv;
            #pragma unroll
            for (int r = 0; r < 4; r++) {
                float m = swishf(aP[0] * a4[0][t][r] + fe[0])
                        + swishf(aP[1] * a4[1][t][r] + fe[1])
                        + swishf(aP[2] * a4[2][t][r] + fe[2])
                        + swishf(aP[3] * a4[3][t][r] + fe[3]);
                const int b = mw * 16 + quad * 4 + r;
                atomicAdd(&agg[(b * Nn + dst) * DMOd + col], m);
            }
        }
    }
}

// ---------- node update MLP + fused next-layer P,Q + agg zeroing ----------
// 16 nodes/block, 128 blocks
__global__ __launch_bounds__(256, 4) void k_updq(
    const float* __restrict__ vC, float* __restrict__ x, float* __restrict__ agg,
    const u16t* __restrict__ U1t, const float* __restrict__ b1,
    const u16t* __restrict__ U2t, const float* __restrict__ b2,
    const u16t* __restrict__ U3t, const float* __restrict__ b3,
    const u16t* __restrict__ U4t, const float* __restrict__ b4,
    const u16t* __restrict__ W1Tn, const float* __restrict__ b1n,
    float* __restrict__ Pn, float* __restrict__ Qn,
    int doPQ) {
    __shared__ u16t uL[16 * UP];   // 8448 B
    __shared__ u16t hL[16 * HP];   // 4352 B
    __shared__ u16t xL[16 * XP];   // 2304 B
    const int g0 = blockIdx.x * 16;
    const int tid = threadIdx.x;
    const int wv = tid >> 6, lane = tid & 63, quad = lane >> 4, l15 = lane & 15;
    const int nBase = wv * 32;

    // stage u = [vec | x | agg/64] as bf16
    {
        const int i = tid >> 4, c0 = (tid & 15) * 16;
        const int g = g0 + i;
        const float* srcp; float scl = 1.f;
        if (c0 < 128)       srcp = &vC[g * OMd + c0];
        else if (c0 < 192)  srcp = &x[g * Fd + (c0 - 128)];
        else              { srcp = &agg[g * DMOd + (c0 - 192)]; scl = 1.0f / 64.0f; }
        bf16x8 s0, s1;
        #pragma unroll
        for (int j = 0; j < 8; j++) {
            s0[j] = (short)f2us(srcp[j] * scl);
            s1[j] = (short)f2us(srcp[8 + j] * scl);
        }
        *(bf16x8*)&uL[i * UP + c0]     = s0;
        *(bf16x8*)&uL[i * UP + c0 + 8] = s1;
    }
    __syncthreads();

    // gemm1: (16x256)@(256x128) -> hL
    {
        f32x4 acc[2];
        #pragma unroll
        for (int t = 0; t < 2; t++) {
            float b0 = b1[nBase + t * 16 + l15];
            acc[t] = (f32x4){b0, b0, b0, b0};
        }
        #pragma unroll
        for (int ks = 0; ks < 8; ks++) {
            bf16x8 a8 = *(const bf16x8*)&uL[l15 * UP + ks * 32 + quad * 8];
            #pragma unroll
            for (int t = 0; t < 2; t++) {
                bf16x8 b8 = *(const bf16x8*)&U1t[(nBase + t * 16 + l15) * 256 + ks * 32 + quad * 8];
                acc[t] = __builtin_amdgcn_mfma_f32_16x16x32_bf16(a8, b8, acc[t], 0, 0, 0);
            }
        }
        #pragma unroll
        for (int t = 0; t < 2; t++)
            #pragma unroll
            for (int r = 0; r < 4; r++)
                hL[(quad * 4 + r) * HP + nBase + t * 16 + l15] = f2us(swishf(acc[t][r]));
    }
    __syncthreads();

    // gemm2, gemm3: (16x128)@(128x128) in-place on hL
    #pragma unroll 1
    for (int st = 0; st < 2; st++) {
        const u16t*  Ut = st ? U3t : U2t;
        const float* bb = st ? b3  : b2;
        f32x4 acc[2];
        #pragma unroll
        for (int t = 0; t < 2; t++) {
            float b0 = bb[nBase + t * 16 + l15];
            acc[t] = (f32x4){b0, b0, b0, b0};
        }
        #pragma unroll
        for (int ks = 0; ks < 4; ks++) {
            bf16x8 a8 = *(const bf16x8*)&hL[l15 * HP + ks * 32 + quad * 8];
            #pragma unroll
            for (int t = 0; t < 2; t++) {
                bf16x8 b8 = *(const bf16x8*)&Ut[(nBase + t * 16 + l15) * 128 + ks * 32 + quad * 8];
                acc[t] = __builtin_amdgcn_mfma_f32_16x16x32_bf16(a8, b8, acc[t], 0, 0, 0);
            }
        }
        __syncthreads();   // all reads of hL done
        #pragma unroll
        for (int t = 0; t < 2; t++)
            #pragma unroll
            for (int r = 0; r < 4; r++)
                hL[(quad * 4 + r) * HP + nBase + t * 16 + l15] = f2us(swishf(acc[t][r]));
        __syncthreads();
    }

    // gemm4: (16x128)@(128x64); residual into x (global fp32 + LDS bf16)
    {
        const int n4 = wv * 16;
        f32x4 acc;
        {
            float b0 = b4[n4 + l15];
            acc = (f32x4){b0, b0, b0, b0};
        }
        #pragma unroll
        for (int ks = 0; ks < 4; ks++) {
            bf16x8 a8 = *(const bf16x8*)&hL[l15 * HP + ks * 32 + quad * 8];
            bf16x8 b8 = *(const bf16x8*)&U4t[(n4 + l15) * 128 + ks * 32 + quad * 8];
            acc = __builtin_amdgcn_mfma_f32_16x16x32_bf16(a8, b8, acc, 0, 0, 0);
        }
        #pragma unroll
        for (int r = 0; r < 4; r++) {
            int row = quad * 4 + r, col = n4 + l15;
            float xn = x[(g0 + row) * Fd + col] + swishf(acc[r]);
            x[(g0 + row) * Fd + col] = xn;
            xL[row * XP + col] = f2us(xn);
        }
    }

    // zero this block's agg rows for the next layer
    {
        int idx = tid;
        #pragma unroll
        for (int k = 0; k < 4; k++, idx += 256) agg[g0 * DMOd + idx] = 0.f;
    }
    __syncthreads();

    // fused next-layer P,Q: (16x64) @ W1T -> P,Q rows; P gets b1 of next layer
    if (doPQ) {
        f32x4 ap[2], aq[2];
        #pragma unroll
        for (int j = 0; j < 2; j++) { ap[j] = (f32x4){0,0,0,0}; aq[j] = (f32x4){0,0,0,0}; }
        #pragma unroll
        for (int ks = 0; ks < 2; ks++) {
            bf16x8 a8 = *(const bf16x8*)&xL[l15 * XP + ks * 32 + quad * 8];
            #pragma unroll
            for (int j = 0; j < 2; j++) {
                const int n0 = (wv * 2 + j) * 16 + l15;
                bf16x8 bp = *(const bf16x8*)&W1Tn[n0 * 128 + ks * 32 + quad * 8];
                bf16x8 bq = *(const bf16x8*)&W1Tn[n0 * 128 + 64 + ks * 32 + quad * 8];
                ap[j] = __builtin_amdgcn_mfma_f32_16x16x32_bf16(a8, bp, ap[j], 0, 0, 0);
                aq[j] = __builtin_amdgcn_mfma_f32_16x16x32_bf16(a8, bq, aq[j], 0, 0, 0);
            }
        }
        #pragma unroll
        for (int j = 0; j < 2; j++)
            #pragma unroll
            for (int r = 0; r < 4; r++) {
                int g = g0 + quad * 4 + r, col = (wv * 2 + j) * 16 + l15;
                Pn[g * DMd + col] = ap[j][r] + b1n[col];
                Qn[g * DMd + col] = aq[j][r];
            }
    }
}

// ---------- pre/post heads -> c, plus v passthrough ----------
__global__ __launch_bounds__(128) void k_final(
    const float* __restrict__ x, const void* __restrict__ vraw,
    const float* __restrict__ pW1, const float* __restrict__ pb1,
    const float* __restrict__ pW2, const float* __restrict__ pb2,
    const float* __restrict__ pW3, const float* __restrict__ pb3,
    const float* __restrict__ pW4, const float* __restrict__ pb4,
    const float* __restrict__ qW1, const float* __restrict__ qb1,
    const float* __restrict__ qW2, const float* __restrict__ qb2,
    float* __restrict__ c_buf, void* __restrict__ out, const void* __restrict__ g1raw) {
    __shared__ float xr[64];
    __shared__ float ha[128];
    __shared__ float hb[128];
    __shared__ float hc[64];
    __shared__ float tt[64];
    const int bn = blockIdx.x;
    const int tid = threadIdx.x;
    const int flag = get_flag(g1raw);
    if (tid < 64) xr[tid] = x[bn * Fd + tid];
    __syncthreads();
    float acc = pb1[tid];
    #pragma unroll 8
    for (int k = 0; k < 64; k++) acc += xr[k] * pW1[k * 128 + tid];
    ha[tid] = swishf(acc);
    __syncthreads();
    acc = pb2[tid];
    #pragma unroll 8
    for (int k = 0; k < 128; k++) acc += ha[k] * pW2[k * 128 + tid];
    hb[tid] = swishf(acc);
    __syncthreads();
    acc = pb3[tid];
    #pragma unroll 8
    for (int k = 0; k < 128; k++) acc += hb[k] * pW3[k * 128 + tid];
    ha[tid] = swishf(acc);
    __syncthreads();
    if (tid < 64) {
        acc = pb4[tid];
        #pragma unroll 8
        for (int k = 0; k < 128; k++) acc += ha[k] * pW4[k * 64 + tid];
        hc[tid] = acc;
    }
    __syncthreads();
    if (tid < 64) {
        acc = qb1[tid];
        #pragma unroll 8
        for (int k = 0; k < 64; k++) acc += hc[k] * qW1[k * 64 + tid];
        tt[tid] = swishf(acc);
    }
    __syncthreads();
    if (tid < 64) {
        float p = tt[tid] * qW2[tid];
        #pragma unroll
        for (int off = 32; off > 0; off >>= 1) p += __shfl_down(p, off);
        if (tid == 0) {
            float cv = p + qb2[0];
            c_buf[bn] = cv;
            const int ci = 4096 + Bn * Nn * OMd + bn;
            if (flag) ((u16t*)out)[ci] = f2us(cv);
            else      ((float*)out)[ci] = cv;
        }
    }
    const int vi = bn * OMd + tid;
    if (flag) ((u16t*)out)[4096 + vi] = ((const u16t*)vraw)[vi];
    else      ((float*)out)[4096 + vi] = ((const float*)vraw)[vi];
}

// ---------- x3[b,d] = sum_n v[b,n,d] * c[b,n] ----------
__global__ __launch_bounds__(128) void k_x3(const float* __restrict__ vC,
                                            const float* __restrict__ c_buf,
                                            void* __restrict__ out,
                                            const void* __restrict__ g1raw) {
    const int b = blockIdx.x, d = threadIdx.x;
    const int flag = get_flag(g1raw);
    float acc = 0.f;
    #pragma unroll 4
    for (int n = 0; n < Nn; n++)
        acc += vC[(b * Nn + n) * OMd + d] * c_buf[b * Nn + n];
    if (flag) ((u16t*)out)[b * OMd + d] = f2us(acc);
    else      ((float*)out)[b * OMd + d] = acc;
}

extern "C" void kernel_launch(void* const* d_in, const int* in_sizes, int n_in,
                              void* d_out, int out_size, void* d_ws, size_t ws_size,
                              hipStream_t stream) {
    float* ws = (float*)d_ws;
    float* C     = ws + 16;
    float* x     = C + 1073664;
    float* P     = x + 131072;
    float* Q     = P + 262144;
    float* agg   = Q + 262144;
    float* c_buf = agg + 131072;
    u16t*  Wt    = (u16t*)(c_buf + 2048);   // 4*WSEG u16 = 1 MB
    float* CS    = (float*)(Wt + 4 * WSEG); // 4*320 fp32 colsums

    Ptrs t;
    for (int i = 0, j = 0; i < 37; i++) {
        if (i == 2) continue;
        t.p[j++] = d_in[i];
    }

    k_prep<<<NB_PREP, 256, 0, stream>>>(t, C, x, Wt, CS, P, Q, agg);

    for (int l = 0; l < 4; l++) {
        u16t* Wl = Wt + l * WSEG;
        float* CSl = CS + l * 320;
        k_edge<<<64 * 16, 256, 0, stream>>>(
            P, Q,
            C + C_G1 + l * En, C + C_BB1 + l * En,
            Wl + S_W2T, C + C_MB2 + l * DMd, CSl,
            C + C_G2 + l * En, C + C_BB2 + l * En,
            Wl + S_W3T, C + C_MB3 + l * DMd, CSl + 128,
            C + C_G3 + l * En, C + C_BB3 + l * En,
            Wl + S_W4T, C + C_MB4 + l * DMOd, CSl + 256,
            agg);
        const int doPQ = (l < 3) ? 1 : 0;
        const u16t* W1Tn = Wt + (doPQ ? (l + 1) : 0) * WSEG + S_W1T;
        const float* b1n = C + C_MB1 + (doPQ ? (l + 1) : 0) * DMd;
        k_updq<<<Bn * Nn / 16, 256, 0, stream>>>(
            C + C_VEC, x, agg,
            Wl + S_U1T, C + C_UB1 + l * DMd,
            Wl + S_U2T, C + C_UB2 + l * DMd,
            Wl + S_U3T, C + C_UB3 + l * DMd,
            Wl + S_U4T, C + C_UB4 + l * DMOd,
            W1Tn, b1n, P, Q, doPQ);
    }

    k_final<<<Bn * Nn, 128, 0, stream>>>(x, d_in[1],
        C + C_PW1, C + C_PB1, C + C_PW2, C + C_PB2,
        C + C_PW3, C + C_PB3, C + C_PW4, C + C_PB4,
        C + C_QW1, C + C_QB1, C + C_QW2, C + C_QB2,
        c_buf, d_out, d_in[5]);
    k_x3<<<Bn, 128, 0, stream>>>(C + C_VEC, c_buf, d_out, d_in[5]);
}